// Round 8
// baseline (189.047 us; speedup 1.0000x reference)
//
#include <hip/hip_runtime.h>

#define BATCH 65536
#define IN_DIM 128
#define INT_NODES 255
#define LEAF 256
#define OUT_DIM 8
#define NBLK (BATCH / 64)   // 1024 blocks x 4 waves x 16 rows/wave
#define AMB_TH 5e-4f

typedef float  f4v __attribute__((ext_vector_type(4)));
typedef short  s8v __attribute__((ext_vector_type(8)));

__device__ __forceinline__ unsigned short bfhi(float f) {
    unsigned u = __builtin_bit_cast(unsigned, f);
    unsigned r = (u + 0x7FFFu + ((u >> 16) & 1u)) >> 16;   // RNE
    return (unsigned short)r;
}
__device__ __forceinline__ float bf2f(unsigned short h) {
    unsigned u = ((unsigned)h) << 16;
    return __builtin_bit_cast(float, u);
}

// Fused prepass: blocks [0,64) = LDS-tiled transpose Wor[o*128+i][l] -> Wor_t[l][o*128+i];
// blocks [64,192) = Wp -> MFMA B-fragments, bf16 hi/lo split, node 255 zero-pad.
__global__ __launch_bounds__(256) void prep(const float* __restrict__ Wor,
                                            float* __restrict__ Wor_t,
                                            const float* __restrict__ Wp,
                                            unsigned short* __restrict__ Bh,
                                            unsigned short* __restrict__ Bl) {
    if (blockIdx.x < 64) {
        __shared__ float t[64][65];
        const int rt = blockIdx.x >> 2, ct = blockIdx.x & 3;  // 16 x 4 tiles of 64x64
        const int r0 = rt * 64, c0 = ct * 64;
        const int tx = threadIdx.x & 63, ty = threadIdx.x >> 6;
#pragma unroll
        for (int p = 0; p < 16; ++p) {
            int r = ty + p * 4;
            t[r][tx] = Wor[(size_t)(r0 + r) * 256 + c0 + tx];     // coalesced
        }
        __syncthreads();
#pragma unroll
        for (int p = 0; p < 16; ++p) {
            int r = ty + p * 4;
            Wor_t[(size_t)(c0 + r) * 1024 + r0 + tx] = t[tx][r];  // coalesced
        }
    } else {
        // B-frag (16x16x32): B[k = ks*32+(lane>>4)*8+j][n = ntg*16+(lane&15)],
        // slot = ((ks*16+ntg)*64+lane)*8+j.
        int slot = (blockIdx.x - 64) * 256 + threadIdx.x;   // 32768
        int j    = slot & 7;
        int lane = (slot >> 3) & 63;
        int ntg  = (slot >> 9) & 15;
        int ks   = slot >> 13;
        int n = ntg * 16 + (lane & 15);
        int k = ks * 32 + (lane >> 4) * 8 + j;
        float v = (n < INT_NODES) ? Wp[n * IN_DIM + k] : 0.f;
        unsigned short h = bfhi(v);
        Bh[slot] = h;
        Bl[slot] = bfhi(v - bf2f(h));
    }
}

// Zero __syncthreads: each wave owns 16 rows x 256 nodes end-to-end.
// (Plain launch_bounds -- R6 showed (256,4) clamps VGPR to 64 and spills.)
__global__ __launch_bounds__(256) void dgt_main(
    const float* __restrict__ x, const float* __restrict__ Wp,
    const float* __restrict__ bp, const unsigned short* __restrict__ Bhg,
    const unsigned short* __restrict__ Blg, const float* __restrict__ Wor_t,
    const float* __restrict__ bor, const float* __restrict__ stds,
    float* __restrict__ out, float* __restrict__ stdo) {

    // Wave-private LDS only (no cross-wave traffic, no barriers): ~17 KB.
    __shared__ unsigned char sgnw[4][LEAF * 16];  // [wave][node*16 + row]
    __shared__ float psw[4][16];
    __shared__ int   leafw[4][16];

    const int tid  = threadIdx.x;
    const int wave = tid >> 6;
    const int lane = tid & 63;
    const int c = lane & 15;          // A-row / C-col within tile
    const int g = lane >> 4;          // k-group / C-row-group
    const int rowbase = blockIdx.x * 64 + wave * 16;

    // ---- MFMA: z[16 x 256] strip. ks outer so 16 independent acc chains. ----
    f4v acc[16];
#pragma unroll
    for (int nt = 0; nt < 16; ++nt) acc[nt] = (f4v){0.f, 0.f, 0.f, 0.f};

    const s8v* Bh8 = (const s8v*)Bhg;
    const s8v* Bl8 = (const s8v*)Blg;
#pragma unroll
    for (int ks = 0; ks < 4; ++ks) {
        // A-frag: A[m=c][k = ks*32 + g*8 + j], split bf16 hi/lo.
        const float* p = x + (size_t)(rowbase + c) * IN_DIM + ks * 32 + g * 8;
        float4 v0 = *reinterpret_cast<const float4*>(p);
        float4 v1 = *reinterpret_cast<const float4*>(p + 4);
        float f[8] = {v0.x, v0.y, v0.z, v0.w, v1.x, v1.y, v1.z, v1.w};
        s8v ah, al;
#pragma unroll
        for (int j = 0; j < 8; ++j) {
            unsigned short h = bfhi(f[j]);
            ah[j] = (short)h;
            al[j] = (short)bfhi(f[j] - bf2f(h));
        }
#pragma unroll
        for (int nt = 0; nt < 16; ++nt) {
            int idx = (ks * 16 + nt) * 64 + lane;   // coalesced, L2-hot
            s8v bh = Bh8[idx];
            s8v bl = Bl8[idx];
            acc[nt] = __builtin_amdgcn_mfma_f32_16x16x32_bf16(ah, bh, acc[nt], 0, 0, 0);
            acc[nt] = __builtin_amdgcn_mfma_f32_16x16x32_bf16(ah, bl, acc[nt], 0, 0, 0);
            acc[nt] = __builtin_amdgcn_mfma_f32_16x16x32_bf16(al, bh, acc[nt], 0, 0, 0);
        }
    }

    // ---- compress: sign/ambig -> wave LDS; |z+bp| partials in-register. ----
    // C/D: col n = nt*16 + c, row m = g*4 + r.
    float asum[4] = {0.f, 0.f, 0.f, 0.f};
#pragma unroll
    for (int nt = 0; nt < 16; ++nt) {
        const int n = nt * 16 + c;
        const float bpv = (n < INT_NODES) ? bp[n] : 0.f;   // L1-hot 1KB
        unsigned pk = 0;
#pragma unroll
        for (int r = 0; r < 4; ++r) {
            float v = acc[nt][r] + bpv;
            float av = fabsf(v);
            if (n < INT_NODES) asum[r] += av;
            pk |= ((v < 0.f ? 1u : 0u) | (av < AMB_TH ? 2u : 0u)) << (8 * r);
        }
        *reinterpret_cast<unsigned*>(&sgnw[wave][n * 16 + g * 4]) = pk;
    }
    // butterfly over the 16 lanes sharing g (masks <16 stay in-group)
#pragma unroll
    for (int m = 1; m < 16; m <<= 1)
#pragma unroll
        for (int r = 0; r < 4; ++r) asum[r] += __shfl_xor(asum[r], m);

    if (c == 0) {   // one writer per row-group: rows g*4+r
#pragma unroll
        for (int r = 0; r < 4; ++r) {
            float fac = asum[r] * (1.0f / (float)INT_NODES);
            // p* of argmax leaf: sum_l exp(and_z_l - 8 fac) = (1 + e^{-2 fac})^8.
            float e = expf(-2.0f * fac);
            float q = 1.0f + e;
            float q2 = q * q, q4 = q2 * q2, q8 = q4 * q4;
            psw[wave][g * 4 + r] = 1.0f / q8;
        }
    }

    // ---- traversal: lanes 0..15, one row each (same wave -> no barrier). ----
    if (lane < 16) {
        int node = 0;
#pragma unroll
        for (int d = 0; d < 8; ++d) {
            unsigned b = sgnw[wave][node * 16 + lane];
            int neg;
            if (b & 2u) {       // rare: exact sign via fp64 from global
                double zd = (double)bp[node];
                const float* wr = Wp + node * IN_DIM;
                const float* xrow = x + (size_t)(rowbase + lane) * IN_DIM;
                for (int k = 0; k < IN_DIM; ++k)
                    zd = fma((double)wr[k], (double)xrow[k], zd);
                neg = (zd < 0.0) ? 1 : 0;
            } else {
                neg = (int)(b & 1u);
            }
            node = 2 * node + 1 + neg;
        }
        leafw[wave][lane] = node - INT_NODES;
    }

    // ---- heads: 4 lanes/row x 2 outputs, full-K fp32 dots (no reduction). ----
    {
        const int rr = lane >> 2;            // row within wave strip
        const int o0 = (lane & 3) * 2;
        const int leaf = leafw[wave][rr];
        const float ps = psw[wave][rr];
        const float* xrow = x + (size_t)(rowbase + rr) * IN_DIM;   // L1/L2-hot
        const float* w0 = Wor_t + (size_t)leaf * 1024 + o0 * IN_DIM;
        const float* w1 = w0 + IN_DIM;
        const float* b0p = bor + o0 * IN_DIM;
        const float* b1p = b0p + IN_DIM;
        float sa0 = 0.f, sa1 = 0.f, sb0 = 0.f, sb1 = 0.f;   // <w,x> o0 / o0+1
        float ta0 = 0.f, ta1 = 0.f, tb0 = 0.f, tb1 = 0.f;   // <bor,x>
#pragma unroll
        for (int ch = 0; ch < IN_DIM; ch += 8) {
            float4 x0 = *reinterpret_cast<const float4*>(xrow + ch);
            float4 x1 = *reinterpret_cast<const float4*>(xrow + ch + 4);
            float4 wa0 = *reinterpret_cast<const float4*>(w0 + ch);
            float4 wa1 = *reinterpret_cast<const float4*>(w0 + ch + 4);
            float4 wb0 = *reinterpret_cast<const float4*>(w1 + ch);
            float4 wb1 = *reinterpret_cast<const float4*>(w1 + ch + 4);
            float4 ca0 = *reinterpret_cast<const float4*>(b0p + ch);
            float4 ca1 = *reinterpret_cast<const float4*>(b0p + ch + 4);
            float4 cb0 = *reinterpret_cast<const float4*>(b1p + ch);
            float4 cb1 = *reinterpret_cast<const float4*>(b1p + ch + 4);
            sa0 = fmaf(wa0.x, x0.x, sa0); sa0 = fmaf(wa0.y, x0.y, sa0);
            sa0 = fmaf(wa0.z, x0.z, sa0); sa0 = fmaf(wa0.w, x0.w, sa0);
            sa1 = fmaf(wa1.x, x1.x, sa1); sa1 = fmaf(wa1.y, x1.y, sa1);
            sa1 = fmaf(wa1.z, x1.z, sa1); sa1 = fmaf(wa1.w, x1.w, sa1);
            sb0 = fmaf(wb0.x, x0.x, sb0); sb0 = fmaf(wb0.y, x0.y, sb0);
            sb0 = fmaf(wb0.z, x0.z, sb0); sb0 = fmaf(wb0.w, x0.w, sb0);
            sb1 = fmaf(wb1.x, x1.x, sb1); sb1 = fmaf(wb1.y, x1.y, sb1);
            sb1 = fmaf(wb1.z, x1.z, sb1); sb1 = fmaf(wb1.w, x1.w, sb1);
            ta0 = fmaf(ca0.x, x0.x, ta0); ta0 = fmaf(ca0.y, x0.y, ta0);
            ta0 = fmaf(ca0.z, x0.z, ta0); ta0 = fmaf(ca0.w, x0.w, ta0);
            ta1 = fmaf(ca1.x, x1.x, ta1); ta1 = fmaf(ca1.y, x1.y, ta1);
            ta1 = fmaf(ca1.z, x1.z, ta1); ta1 = fmaf(ca1.w, x1.w, ta1);
            tb0 = fmaf(cb0.x, x0.x, tb0); tb0 = fmaf(cb0.y, x0.y, tb0);
            tb0 = fmaf(cb0.z, x0.z, tb0); tb0 = fmaf(cb0.w, x0.w, tb0);
            tb1 = fmaf(cb1.x, x1.x, tb1); tb1 = fmaf(cb1.y, x1.y, tb1);
            tb1 = fmaf(cb1.z, x1.z, tb1); tb1 = fmaf(cb1.w, x1.w, tb1);
        }
        const size_t ob = (size_t)(rowbase + rr) * OUT_DIM + o0;
        float2 ov; ov.x = ps * (sa0 + sa1) + (ta0 + ta1);
        ov.y = ps * (sb0 + sb1) + (tb0 + tb1);
        *reinterpret_cast<float2*>(out + ob) = ov;
        float2 sv;
        sv.x = fminf(fmaxf(ps * stds[leaf * OUT_DIM + o0], -20.0f), 2.0f);
        sv.y = fminf(fmaxf(ps * stds[leaf * OUT_DIM + o0 + 1], -20.0f), 2.0f);
        *reinterpret_cast<float2*>(stdo + ob) = sv;
    }
}

extern "C" void kernel_launch(void* const* d_in, const int* in_sizes, int n_in,
                              void* d_out, int out_size, void* d_ws, size_t ws_size,
                              hipStream_t stream) {
    const float* x    = (const float*)d_in[0];
    const float* Wp   = (const float*)d_in[1];
    const float* bp   = (const float*)d_in[2];
    // d_in[3] = Wand -- folded into the traversal, unused.
    const float* Wor  = (const float*)d_in[4];
    const float* bor  = (const float*)d_in[5];
    const float* stds = (const float*)d_in[6];
    float* out = (float*)d_out;

    float* wor_t = (float*)d_ws;                                              // 1 MB
    unsigned short* Bh = (unsigned short*)((char*)d_ws + (1 << 20));          // 64 KB
    unsigned short* Bl = (unsigned short*)((char*)d_ws + (1 << 20) + (64 << 10)); // 64 KB

    prep<<<192, 256, 0, stream>>>(Wor, wor_t, Wp, Bh, Bl);
    dgt_main<<<NBLK, 256, 0, stream>>>(x, Wp, bp, Bh, Bl, wor_t, bor, stds,
                                       out, out + (size_t)BATCH * OUT_DIM);
}